// Round 1
// baseline (381.267 us; speedup 1.0000x reference)
//
#include <hip/hip_runtime.h>
#include <cstdint>
#include <math.h>

#define BATCH 32
#define NPIX (512*512)      // 262144 pixels per batch
#define NBINS 65536         // 16-bit radix level

// Small per-batch state, lives in ws right after the two histograms.
struct SmallState {
    int      sel1[BATCH];   // selected top-16 prefix (-1 if no fg)
    uint32_t rem1[BATCH];   // rank within selected prefix bin (1-based)
    float    thr [BATCH];   // final threshold value
    double   accI[BATCH];   // intersection sums
    double   accU[BATCH];   // union sums
};

// Compute p (softmax channel 1) and tp = p*(t+eps), exactly mirroring
// jax.nn.softmax's max-subtract formulation.
__device__ __forceinline__ void compute_p_tp(float l0, float l1, float t, float e,
                                             float& p, float& tp, bool& fg) {
    float m  = fmaxf(l0, l1);
    float e0 = expf(l0 - m);
    float e1 = expf(l1 - m);
    p  = e1 / (e0 + e1);
    tp = p * (t + e);
    fg = (t == 1.0f);
}

// Pass 1: compute p/tp, optional store, level-1 histogram (top 16 bits).
__global__ __launch_bounds__(256)
void k_compute_hist1(const float* __restrict__ logits,
                     const float* __restrict__ target,
                     const float* __restrict__ eps,
                     uint32_t* __restrict__ hist1,
                     float* __restrict__ pbuf,    // nullable
                     float* __restrict__ tpbuf)   // nullable (tp if fg else -1)
{
    const int b  = blockIdx.y;
    const int i0 = (blockIdx.x * blockDim.x + threadIdx.x) * 4;
    const size_t lbase = (size_t)b * 2 * NPIX;
    const size_t nbase = (size_t)b * NPIX;

    float4 l0 = *(const float4*)(logits + lbase + i0);
    float4 l1 = *(const float4*)(logits + lbase + NPIX + i0);
    float4 tt = *(const float4*)(target + nbase + i0);
    float4 ee = *(const float4*)(eps    + nbase + i0);

    float a0[4] = {l0.x, l0.y, l0.z, l0.w};
    float a1[4] = {l1.x, l1.y, l1.z, l1.w};
    float tv[4] = {tt.x, tt.y, tt.z, tt.w};
    float ev[4] = {ee.x, ee.y, ee.z, ee.w};

    float pv[4], tpv[4];
    uint32_t* hb = hist1 + (size_t)b * NBINS;

#pragma unroll
    for (int j = 0; j < 4; ++j) {
        float p, tp; bool fg;
        compute_p_tp(a0[j], a1[j], tv[j], ev[j], p, tp, fg);
        pv[j]  = p;
        tpv[j] = fg ? tp : -1.0f;
        if (fg) {
            atomicAdd(hb + (__float_as_uint(tp) >> 16), 1u);
        }
    }
    if (pbuf) {
        *(float4*)(pbuf  + nbase + i0) = make_float4(pv[0],  pv[1],  pv[2],  pv[3]);
        *(float4*)(tpbuf + nbase + i0) = make_float4(tpv[0], tpv[1], tpv[2], tpv[3]);
    }
}

// Level-1 scan: one block per batch. Two-level parallel prefix over 65536 bins.
__global__ __launch_bounds__(256)
void k_scan1(const uint32_t* __restrict__ hist1,
             int* __restrict__ sel1, uint32_t* __restrict__ rem1)
{
    const int b = blockIdx.x;
    const int t = threadIdx.x;
    const uint32_t* h = hist1 + (size_t)b * NBINS;

    __shared__ uint32_t part[256];
    __shared__ uint32_t sChunk, sExclChunk;

    // chunk t = bins [t*256, t*256+256)
    uint32_t s = 0;
    const uint4* hv = (const uint4*)h;
    for (int j = 0; j < 64; ++j) {
        uint4 v = hv[t * 64 + j];
        s += v.x + v.y + v.z + v.w;
    }
    part[t] = s;
    __syncthreads();
    for (int off = 1; off < 256; off <<= 1) {
        uint32_t v = (t >= off) ? part[t - off] : 0u;
        __syncthreads();
        part[t] += v;
        __syncthreads();
    }
    uint32_t incl = part[t], excl = incl - s;
    uint32_t total = part[255];

    if (total == 0) {
        if (t == 0) { sel1[b] = -1; rem1[b] = 0; }
        return;
    }
    uint32_t k = total / 2;           // max(1, n_fg/2)
    if (k == 0) k = 1;

    if (excl < k && k <= incl) { sChunk = t; sExclChunk = excl; }
    __syncthreads();
    uint32_t c = sChunk, exclChunk = sExclChunk;

    // level 2: one thread per bin of the selected chunk
    uint32_t v2 = h[c * 256 + t];
    __syncthreads();
    part[t] = v2;
    __syncthreads();
    for (int off = 1; off < 256; off <<= 1) {
        uint32_t v = (t >= off) ? part[t - off] : 0u;
        __syncthreads();
        part[t] += v;
        __syncthreads();
    }
    uint32_t incl2 = part[t], excl2 = incl2 - v2;
    uint32_t kk = k - exclChunk;
    if (excl2 < kk && kk <= incl2) {
        sel1[b] = (int)(c * 256 + t);
        rem1[b] = kk - excl2;          // 1-based rank within this bin
    }
}

// Pass 2: level-2 histogram (low 16 bits) restricted to the selected prefix.
__global__ __launch_bounds__(256)
void k_hist2(const float* __restrict__ logits,
             const float* __restrict__ target,
             const float* __restrict__ eps,
             const float* __restrict__ tpbuf,    // nullable
             const int* __restrict__ sel1,
             uint32_t* __restrict__ hist2)
{
    const int b = blockIdx.y;
    const int pfx = sel1[b];
    if (pfx < 0) return;
    const int i0 = (blockIdx.x * blockDim.x + threadIdx.x) * 4;
    const size_t nbase = (size_t)b * NPIX;
    uint32_t* hb = hist2 + (size_t)b * NBINS;

    if (tpbuf) {
        float4 tp4 = *(const float4*)(tpbuf + nbase + i0);
        float tpv[4] = {tp4.x, tp4.y, tp4.z, tp4.w};
#pragma unroll
        for (int j = 0; j < 4; ++j) {
            if (tpv[j] >= 0.0f) {
                uint32_t bits = __float_as_uint(tpv[j]);
                if ((int)(bits >> 16) == pfx)
                    atomicAdd(hb + (bits & 0xFFFFu), 1u);
            }
        }
    } else {
        const size_t lbase = (size_t)b * 2 * NPIX;
        float4 l0 = *(const float4*)(logits + lbase + i0);
        float4 l1 = *(const float4*)(logits + lbase + NPIX + i0);
        float4 tt = *(const float4*)(target + nbase + i0);
        float4 ee = *(const float4*)(eps    + nbase + i0);
        float a0[4] = {l0.x, l0.y, l0.z, l0.w};
        float a1[4] = {l1.x, l1.y, l1.z, l1.w};
        float tv[4] = {tt.x, tt.y, tt.z, tt.w};
        float ev[4] = {ee.x, ee.y, ee.z, ee.w};
#pragma unroll
        for (int j = 0; j < 4; ++j) {
            float p, tp; bool fg;
            compute_p_tp(a0[j], a1[j], tv[j], ev[j], p, tp, fg);
            if (fg) {
                uint32_t bits = __float_as_uint(tp);
                if ((int)(bits >> 16) == pfx)
                    atomicAdd(hb + (bits & 0xFFFFu), 1u);
            }
        }
    }
}

// Level-2 scan: produce the exact threshold value.
__global__ __launch_bounds__(256)
void k_scan2(const uint32_t* __restrict__ hist2,
             const int* __restrict__ sel1,
             const uint32_t* __restrict__ rem1,
             float* __restrict__ thr)
{
    const int b = blockIdx.x;
    const int t = threadIdx.x;
    const int pfx = sel1[b];
    if (pfx < 0) { if (t == 0) thr[b] = INFINITY; return; }
    const uint32_t* h = hist2 + (size_t)b * NBINS;
    const uint32_t k = rem1[b];

    __shared__ uint32_t part[256];
    __shared__ uint32_t sChunk, sExclChunk;

    uint32_t s = 0;
    const uint4* hv = (const uint4*)h;
    for (int j = 0; j < 64; ++j) {
        uint4 v = hv[t * 64 + j];
        s += v.x + v.y + v.z + v.w;
    }
    part[t] = s;
    __syncthreads();
    for (int off = 1; off < 256; off <<= 1) {
        uint32_t v = (t >= off) ? part[t - off] : 0u;
        __syncthreads();
        part[t] += v;
        __syncthreads();
    }
    uint32_t incl = part[t], excl = incl - s;
    if (excl < k && k <= incl) { sChunk = t; sExclChunk = excl; }
    __syncthreads();
    uint32_t c = sChunk, exclChunk = sExclChunk;

    uint32_t v2 = h[c * 256 + t];
    __syncthreads();
    part[t] = v2;
    __syncthreads();
    for (int off = 1; off < 256; off <<= 1) {
        uint32_t v = (t >= off) ? part[t - off] : 0u;
        __syncthreads();
        part[t] += v;
        __syncthreads();
    }
    uint32_t incl2 = part[t], excl2 = incl2 - v2;
    uint32_t kk = k - exclChunk;
    if (excl2 < kk && kk <= incl2) {
        uint32_t bits = ((uint32_t)pfx << 16) | (uint32_t)(c * 256 + t);
        thr[b] = __uint_as_float(bits);
    }
}

// Pass 3: masked dice sums with f64 block reduction.
__global__ __launch_bounds__(256)
void k_final(const float* __restrict__ logits,
             const float* __restrict__ target,
             const float* __restrict__ eps,
             const float* __restrict__ pbuf,     // nullable
             const float* __restrict__ tpbuf,    // nullable
             const float* __restrict__ thr,
             double* __restrict__ accI, double* __restrict__ accU)
{
    const int b  = blockIdx.y;
    const int t  = threadIdx.x;
    const int i0 = (blockIdx.x * blockDim.x + t) * 4;
    const size_t nbase = (size_t)b * NPIX;
    const float T = thr[b];

    float pv[4], tpv[4];
    if (pbuf) {
        float4 p4  = *(const float4*)(pbuf  + nbase + i0);
        float4 tp4 = *(const float4*)(tpbuf + nbase + i0);
        pv[0]=p4.x; pv[1]=p4.y; pv[2]=p4.z; pv[3]=p4.w;
        tpv[0]=tp4.x; tpv[1]=tp4.y; tpv[2]=tp4.z; tpv[3]=tp4.w;
    } else {
        const size_t lbase = (size_t)b * 2 * NPIX;
        float4 l0 = *(const float4*)(logits + lbase + i0);
        float4 l1 = *(const float4*)(logits + lbase + NPIX + i0);
        float4 tt = *(const float4*)(target + nbase + i0);
        float4 ee = *(const float4*)(eps    + nbase + i0);
        float a0[4] = {l0.x, l0.y, l0.z, l0.w};
        float a1[4] = {l1.x, l1.y, l1.z, l1.w};
        float tv[4] = {tt.x, tt.y, tt.z, tt.w};
        float ev[4] = {ee.x, ee.y, ee.z, ee.w};
#pragma unroll
        for (int j = 0; j < 4; ++j) {
            float p, tp; bool fg;
            compute_p_tp(a0[j], a1[j], tv[j], ev[j], p, tp, fg);
            pv[j]  = p;
            tpv[j] = fg ? tp : -1.0f;
        }
    }

    double I = 0.0, U = 0.0;
#pragma unroll
    for (int j = 0; j < 4; ++j) {
        float p = pv[j];
        if (tpv[j] >= 0.0f) {            // foreground
            if (!(tpv[j] > T)) {         // kept (ties kept, matching reference)
                I += (double)p;
                U += (double)p * (double)p + 1.0;
            }
        } else {                          // background: mask=1, target=0
            U += (double)p * (double)p;
        }
    }

    __shared__ double sI[256];
    __shared__ double sU[256];
    sI[t] = I; sU[t] = U;
    __syncthreads();
    for (int off = 128; off > 0; off >>= 1) {
        if (t < off) { sI[t] += sI[t + off]; sU[t] += sU[t + off]; }
        __syncthreads();
    }
    if (t == 0) {
        atomicAdd(&accI[b], sI[0]);
        atomicAdd(&accU[b], sU[0]);
    }
}

__global__ void k_finalize(const double* __restrict__ accI,
                           const double* __restrict__ accU,
                           float* __restrict__ out)
{
    const int t = threadIdx.x;
    double d = 0.0;
    if (t < BATCH) {
        double I = accI[t], U = accU[t];
        d = (2.0 * I + 1e-5) / (U + 1e-5);
    }
    for (int off = 32; off > 0; off >>= 1) d += __shfl_down(d, off);
    if (t == 0) out[0] = (float)(1.0 - d / (double)BATCH);
}

extern "C" void kernel_launch(void* const* d_in, const int* in_sizes, int n_in,
                              void* d_out, int out_size, void* d_ws, size_t ws_size,
                              hipStream_t stream) {
    const float* logits = (const float*)d_in[0];
    const float* target = (const float*)d_in[1];
    const float* eps    = (const float*)d_in[2];
    float* out = (float*)d_out;

    char* ws = (char*)d_ws;
    const size_t histBytes = (size_t)BATCH * NBINS * 4;   // 8 MB each
    uint32_t* hist1 = (uint32_t*)ws;
    uint32_t* hist2 = (uint32_t*)(ws + histBytes);
    SmallState* sm  = (SmallState*)(ws + 2 * histBytes);
    const size_t baseNeed = 2 * histBytes + sizeof(SmallState);

    // Optional store path: keep p and tp_fg to avoid recomputation passes.
    float* pbuf = nullptr;
    float* tpbuf = nullptr;
    const size_t storeOff  = ((baseNeed + 255) / 256) * 256;
    const size_t storeNeed = storeOff + 2 * (size_t)BATCH * NPIX * 4;  // +64 MB
    if (ws_size >= storeNeed) {
        pbuf  = (float*)(ws + storeOff);
        tpbuf = pbuf + (size_t)BATCH * NPIX;
    }

    // Zero histograms + small state (graph-capture-safe).
    hipMemsetAsync(ws, 0, baseNeed, stream);

    dim3 grid(NPIX / (256 * 4), BATCH);   // 256 x 32 blocks
    k_compute_hist1<<<grid, 256, 0, stream>>>(logits, target, eps, hist1, pbuf, tpbuf);
    k_scan1<<<BATCH, 256, 0, stream>>>(hist1, sm->sel1, sm->rem1);
    k_hist2<<<grid, 256, 0, stream>>>(logits, target, eps, tpbuf, sm->sel1, hist2);
    k_scan2<<<BATCH, 256, 0, stream>>>(hist2, sm->sel1, sm->rem1, sm->thr);
    k_final<<<grid, 256, 0, stream>>>(logits, target, eps, pbuf, tpbuf, sm->thr,
                                      sm->accI, sm->accU);
    k_finalize<<<1, 64, 0, stream>>>(sm->accI, sm->accU, out);
}

// Round 3
// 87.983 us; speedup vs baseline: 4.3334x; 4.3334x over previous
//
#include <hip/hip_runtime.h>
#include <cstdint>
#include <math.h>

#define BATCH 32
#define NPIX (512*512)        // 262144 pixels per batch
#define NB1 2048              // level-1 bins: tp bits [31:21]
#define NB2 2048              // level-2 bins: tp bits [20:10]
#define NB3 1024              // level-3 bins: tp bits [9:0]
#define PXB 4096              // pixels per block (256 thr * 16 px)

// Per-batch small state (zeroed each call together with the histograms).
struct SmallState {
    int      pfx1[BATCH];     // selected 11-bit prefix (-1 if no fg)
    uint32_t k2  [BATCH];     // remaining rank for level 2 (1-based)
    int      pfx2[BATCH];     // selected 22-bit prefix (-1 if no fg)
    uint32_t k3  [BATCH];     // remaining rank for level 3 (1-based)
    float    thr [BATCH];     // final threshold value
    double   accI[BATCH];
    double   accU[BATCH];
};

__device__ __forceinline__ void compute_p_tp(float l0, float l1, float t, float e,
                                             float& p, float& tp, bool& fg) {
    float m  = fmaxf(l0, l1);
    float e0 = expf(l0 - m);
    float e1 = expf(l1 - m);
    p  = e1 / (e0 + e1);
    tp = p * (t + e);
    fg = (t == 1.0f);
}

// ---------------------------------------------------------------------------
// Pass 1: compute p/tp, store both, LDS-privatized level-1 histogram.
// ---------------------------------------------------------------------------
__global__ __launch_bounds__(256)
void k_pass1(const float* __restrict__ logits,
             const float* __restrict__ target,
             const float* __restrict__ eps,
             float* __restrict__ pbuf,
             float* __restrict__ tpbuf,     // tp if fg else -1.0f
             uint32_t* __restrict__ hist1)
{
    __shared__ uint32_t lh[NB1];
    const int tid = threadIdx.x;
    for (int i = tid; i < NB1; i += 256) lh[i] = 0;
    __syncthreads();

    const int b = blockIdx.y;
    const size_t nbase = (size_t)b * NPIX;
    const size_t lbase = (size_t)b * 2 * NPIX;
    const int base = blockIdx.x * PXB;

#pragma unroll
    for (int it = 0; it < 4; ++it) {
        const int i0 = base + (it * 256 + tid) * 4;
        float4 l0 = *(const float4*)(logits + lbase + i0);
        float4 l1 = *(const float4*)(logits + lbase + NPIX + i0);
        float4 tt = *(const float4*)(target + nbase + i0);
        float4 ee = *(const float4*)(eps    + nbase + i0);
        float a0[4] = {l0.x, l0.y, l0.z, l0.w};
        float a1[4] = {l1.x, l1.y, l1.z, l1.w};
        float tv[4] = {tt.x, tt.y, tt.z, tt.w};
        float ev[4] = {ee.x, ee.y, ee.z, ee.w};
        float pv[4], tpv[4];
#pragma unroll
        for (int j = 0; j < 4; ++j) {
            float p, tp; bool fg;
            compute_p_tp(a0[j], a1[j], tv[j], ev[j], p, tp, fg);
            pv[j]  = p;
            tpv[j] = fg ? tp : -1.0f;
            if (fg) atomicAdd(&lh[__float_as_uint(tp) >> 21], 1u);
        }
        *(float4*)(pbuf  + nbase + i0) = make_float4(pv[0], pv[1], pv[2], pv[3]);
        *(float4*)(tpbuf + nbase + i0) = make_float4(tpv[0], tpv[1], tpv[2], tpv[3]);
    }

    __syncthreads();
    uint32_t* hb = hist1 + (size_t)b * NB1;
    for (int i = tid; i < NB1; i += 256) {
        uint32_t v = lh[i];
        if (v) atomicAdd(hb + i, v);
    }
}

// ---------------------------------------------------------------------------
// Level-2 histogram: bits [20:10] of tp, restricted to selected 11-bit prefix.
// ---------------------------------------------------------------------------
__global__ __launch_bounds__(256)
void k_hist2(const float* __restrict__ tpbuf,
             const int* __restrict__ pfx1,
             uint32_t* __restrict__ hist2)
{
    const int b = blockIdx.y;
    const int pfx = pfx1[b];
    if (pfx < 0) return;

    __shared__ uint32_t lh[NB2];
    const int tid = threadIdx.x;
    for (int i = tid; i < NB2; i += 256) lh[i] = 0;
    __syncthreads();

    const size_t nbase = (size_t)b * NPIX;
    const int base = blockIdx.x * PXB;
#pragma unroll
    for (int it = 0; it < 4; ++it) {
        const int i0 = base + (it * 256 + tid) * 4;
        float4 tp4 = *(const float4*)(tpbuf + nbase + i0);
        float tpv[4] = {tp4.x, tp4.y, tp4.z, tp4.w};
#pragma unroll
        for (int j = 0; j < 4; ++j) {
            uint32_t bits = __float_as_uint(tpv[j]);
            // background marker -1.0f has the sign bit set -> bits>>21 >= 1024,
            // while pfx <= 1023, so it can never match.
            if ((int)(bits >> 21) == pfx)
                atomicAdd(&lh[(bits >> 10) & (NB2 - 1)], 1u);
        }
    }

    __syncthreads();
    uint32_t* hb = hist2 + (size_t)b * NB2;
    for (int i = tid; i < NB2; i += 256) {
        uint32_t v = lh[i];
        if (v) atomicAdd(hb + i, v);
    }
}

// ---------------------------------------------------------------------------
// Level-3 histogram: bits [9:0] of tp, restricted to selected 22-bit prefix.
// ---------------------------------------------------------------------------
__global__ __launch_bounds__(256)
void k_hist3(const float* __restrict__ tpbuf,
             const int* __restrict__ pfx2,
             uint32_t* __restrict__ hist3)
{
    const int b = blockIdx.y;
    const int pfx = pfx2[b];
    if (pfx < 0) return;

    __shared__ uint32_t lh[NB3];
    const int tid = threadIdx.x;
    for (int i = tid; i < NB3; i += 256) lh[i] = 0;
    __syncthreads();

    const size_t nbase = (size_t)b * NPIX;
    const int base = blockIdx.x * PXB;
#pragma unroll
    for (int it = 0; it < 4; ++it) {
        const int i0 = base + (it * 256 + tid) * 4;
        float4 tp4 = *(const float4*)(tpbuf + nbase + i0);
        float tpv[4] = {tp4.x, tp4.y, tp4.z, tp4.w};
#pragma unroll
        for (int j = 0; j < 4; ++j) {
            uint32_t bits = __float_as_uint(tpv[j]);
            if ((int)(bits >> 10) == pfx)
                atomicAdd(&lh[bits & (NB3 - 1)], 1u);
        }
    }

    __syncthreads();
    uint32_t* hb = hist3 + (size_t)b * NB3;
    for (int i = tid; i < NB3; i += 256) {
        uint32_t v = lh[i];
        if (v) atomicAdd(hb + i, v);
    }
}

// ---------------------------------------------------------------------------
// Scans: one block per batch, 256 threads, parallel prefix + winner walk.
// ---------------------------------------------------------------------------
#define SELECT_BIN(h, nb, k, outBin, outRem)                                  \
    {                                                                         \
        const int g = (nb) / 256;                                             \
        uint32_t s = 0;                                                       \
        for (int j = 0; j < g; ++j) s += (h)[t * g + j];                      \
        part[t] = s;                                                          \
        __syncthreads();                                                      \
        for (int off = 1; off < 256; off <<= 1) {                             \
            uint32_t v = (t >= off) ? part[t - off] : 0u;                     \
            __syncthreads();                                                  \
            part[t] += v;                                                     \
            __syncthreads();                                                  \
        }                                                                     \
        uint32_t incl = part[t], excl = incl - s;                             \
        if (excl < (k) && (k) <= incl) {                                      \
            uint32_t run = excl;                                              \
            for (int j = 0; j < g; ++j) {                                     \
                uint32_t c = (h)[t * g + j];                                  \
                if (run < (k) && (k) <= run + c) {                            \
                    sBin = t * g + j;                                         \
                    sRem = (k) - run;                                         \
                    break;                                                    \
                }                                                             \
                run += c;                                                     \
            }                                                                 \
        }                                                                     \
        __syncthreads();                                                      \
        outBin = sBin;                                                        \
        outRem = sRem;                                                        \
    }

__global__ __launch_bounds__(256)
void k_scan1(const uint32_t* __restrict__ hist1, SmallState* sm)
{
    const int b = blockIdx.x;
    const int t = threadIdx.x;
    const uint32_t* h = hist1 + (size_t)b * NB1;
    __shared__ uint32_t part[256];
    __shared__ int sBin; __shared__ uint32_t sRem;

    // total = n_fg
    uint32_t s = 0;
    for (int j = 0; j < NB1 / 256; ++j) s += h[t * (NB1 / 256) + j];
    part[t] = s;
    __syncthreads();
    for (int off = 1; off < 256; off <<= 1) {
        uint32_t v = (t >= off) ? part[t - off] : 0u;
        __syncthreads();
        part[t] += v;
        __syncthreads();
    }
    uint32_t incl = part[t], excl = incl - s;
    uint32_t total = part[255];
    if (total == 0) {
        if (t == 0) { sm->pfx1[b] = -1; sm->pfx2[b] = -1; sm->thr[b] = INFINITY; }
        return;
    }
    uint32_t k = total / 2;
    if (k == 0) k = 1;

    if (excl < k && k <= incl) {
        uint32_t run = excl;
        for (int j = 0; j < NB1 / 256; ++j) {
            uint32_t c = h[t * (NB1 / 256) + j];
            if (run < k && k <= run + c) { sBin = t * (NB1 / 256) + j; sRem = k - run; break; }
            run += c;
        }
    }
    __syncthreads();
    if (t == 0) { sm->pfx1[b] = sBin; sm->k2[b] = sRem; }
}

__global__ __launch_bounds__(256)
void k_scan2(const uint32_t* __restrict__ hist2, SmallState* sm)
{
    const int b = blockIdx.x;
    const int t = threadIdx.x;
    const int pfx = sm->pfx1[b];
    if (pfx < 0) return;
    const uint32_t* h = hist2 + (size_t)b * NB2;
    const uint32_t k = sm->k2[b];
    __shared__ uint32_t part[256];
    __shared__ int sBin; __shared__ uint32_t sRem;
    int bin; uint32_t rem;
    SELECT_BIN(h, NB2, k, bin, rem);
    if (t == 0) { sm->pfx2[b] = (pfx << 11) | bin; sm->k3[b] = rem; }
}

__global__ __launch_bounds__(256)
void k_scan3(const uint32_t* __restrict__ hist3, SmallState* sm)
{
    const int b = blockIdx.x;
    const int t = threadIdx.x;
    const int pfx = sm->pfx2[b];
    if (pfx < 0) return;
    const uint32_t* h = hist3 + (size_t)b * NB3;
    const uint32_t k = sm->k3[b];
    __shared__ uint32_t part[256];
    __shared__ int sBin; __shared__ uint32_t sRem;
    int bin; uint32_t rem;
    SELECT_BIN(h, NB3, k, bin, rem);
    (void)rem;
    if (t == 0) sm->thr[b] = __uint_as_float(((uint32_t)pfx << 10) | (uint32_t)bin);
}

// ---------------------------------------------------------------------------
// Final: masked dice sums, f64 block reduction, one atomic pair per block.
// ---------------------------------------------------------------------------
__global__ __launch_bounds__(256)
void k_final(const float* __restrict__ pbuf,
             const float* __restrict__ tpbuf,
             const SmallState* __restrict__ sm,
             double* __restrict__ accI, double* __restrict__ accU)
{
    const int b = blockIdx.y;
    const int t = threadIdx.x;
    const size_t nbase = (size_t)b * NPIX;
    const int base = blockIdx.x * PXB;
    const float T = sm->thr[b];

    double I = 0.0, U = 0.0;
#pragma unroll
    for (int it = 0; it < 4; ++it) {
        const int i0 = base + (it * 256 + t) * 4;
        float4 p4  = *(const float4*)(pbuf  + nbase + i0);
        float4 tp4 = *(const float4*)(tpbuf + nbase + i0);
        float pv[4]  = {p4.x, p4.y, p4.z, p4.w};
        float tpv[4] = {tp4.x, tp4.y, tp4.z, tp4.w};
#pragma unroll
        for (int j = 0; j < 4; ++j) {
            float p = pv[j];
            if (tpv[j] >= 0.0f) {            // foreground
                if (!(tpv[j] > T)) {         // kept (ties kept)
                    I += (double)p;
                    U += (double)p * (double)p + 1.0;
                }
            } else {                          // background
                U += (double)p * (double)p;
            }
        }
    }

    __shared__ double sI[256];
    __shared__ double sU[256];
    sI[t] = I; sU[t] = U;
    __syncthreads();
    for (int off = 128; off > 0; off >>= 1) {
        if (t < off) { sI[t] += sI[t + off]; sU[t] += sU[t + off]; }
        __syncthreads();
    }
    if (t == 0) {
        atomicAdd(&accI[b], sI[0]);
        atomicAdd(&accU[b], sU[0]);
    }
}

__global__ void k_finalize(const double* __restrict__ accI,
                           const double* __restrict__ accU,
                           float* __restrict__ out)
{
    const int t = threadIdx.x;
    double d = 0.0;
    if (t < BATCH) {
        double I = accI[t], U = accU[t];
        d = (2.0 * I + 1e-5) / (U + 1e-5);
    }
    for (int off = 32; off > 0; off >>= 1) d += __shfl_down(d, off);
    if (t == 0) out[0] = (float)(1.0 - d / (double)BATCH);
}

// ---------------------------------------------------------------------------
extern "C" void kernel_launch(void* const* d_in, const int* in_sizes, int n_in,
                              void* d_out, int out_size, void* d_ws, size_t ws_size,
                              hipStream_t stream) {
    const float* logits = (const float*)d_in[0];
    const float* target = (const float*)d_in[1];
    const float* eps    = (const float*)d_in[2];
    float* out = (float*)d_out;

    char* ws = (char*)d_ws;
    const size_t h1B = (size_t)BATCH * NB1 * 4;   // 256 KB
    const size_t h2B = (size_t)BATCH * NB2 * 4;   // 256 KB
    const size_t h3B = (size_t)BATCH * NB3 * 4;   // 128 KB
    uint32_t* hist1 = (uint32_t*)ws;
    uint32_t* hist2 = (uint32_t*)(ws + h1B);
    uint32_t* hist3 = (uint32_t*)(ws + h1B + h2B);
    SmallState* sm  = (SmallState*)(ws + h1B + h2B + h3B);
    const size_t baseNeed = h1B + h2B + h3B + sizeof(SmallState);

    const size_t storeOff = ((baseNeed + 255) / 256) * 256;
    float* pbuf  = (float*)(ws + storeOff);
    float* tpbuf = pbuf + (size_t)BATCH * NPIX;

    // Zero histograms + state each call (graph-capture safe).
    hipMemsetAsync(ws, 0, baseNeed, stream);

    dim3 grid(NPIX / PXB, BATCH);   // 64 x 32 = 2048 blocks
    k_pass1<<<grid, 256, 0, stream>>>(logits, target, eps, pbuf, tpbuf, hist1);
    k_scan1<<<BATCH, 256, 0, stream>>>(hist1, sm);
    k_hist2<<<grid, 256, 0, stream>>>(tpbuf, sm->pfx1, hist2);
    k_scan2<<<BATCH, 256, 0, stream>>>(hist2, sm);
    k_hist3<<<grid, 256, 0, stream>>>(tpbuf, sm->pfx2, hist3);
    k_scan3<<<BATCH, 256, 0, stream>>>(hist3, sm);
    k_final<<<grid, 256, 0, stream>>>(pbuf, tpbuf, sm, sm->accI, sm->accU);
    k_finalize<<<1, 64, 0, stream>>>(sm->accI, sm->accU, out);
}